// Round 1
// baseline (168.181 us; speedup 1.0000x reference)
//
#include <hip/hip_runtime.h>
#include <hip/hip_bf16.h>
#include <cstdint>
#include <cmath>

#define B_ 512
#define T_ 256
#define C_ 256
#define HS_ 64

typedef short bf16x8 __attribute__((ext_vector_type(8)));
typedef float f32x4 __attribute__((ext_vector_type(4)));

static __device__ __forceinline__ unsigned short f2bf(float f) {
    union { float f; unsigned int u; } v; v.f = f;
    unsigned int r = v.u + 0x7fffu + ((v.u >> 16) & 1u);
    return (unsigned short)(r >> 16);
}

static __device__ __forceinline__ bf16x8 cvt8(const float4& a, const float4& b) {
    bf16x8 r;
    r[0] = (short)f2bf(a.x); r[1] = (short)f2bf(a.y);
    r[2] = (short)f2bf(a.z); r[3] = (short)f2bf(a.w);
    r[4] = (short)f2bf(b.x); r[5] = (short)f2bf(b.y);
    r[6] = (short)f2bf(b.z); r[7] = (short)f2bf(b.w);
    return r;
}

// ---- Kernel 0: W transpose + bf16 convert: WT[w][n][k] = W_w[k][n] ----
__global__ void wt_kernel(const float* __restrict__ Wq, const float* __restrict__ Wk,
                          const float* __restrict__ Wv, unsigned short* __restrict__ WT) {
    int idx = blockIdx.x * 256 + threadIdx.x;
    if (idx >= 3 * HS_ * C_) return;
    int w = idx / (HS_ * C_);
    int rem = idx - w * (HS_ * C_);
    int n = rem / C_;
    int k = rem - n * C_;
    const float* W = (w == 0) ? Wq : ((w == 1) ? Wk : Wv);
    WT[idx] = f2bf(W[k * HS_ + n]);
}

// ---- Kernel 1: projection GEMM. Q/K/V bf16 [B*T][64] ----
__global__ __launch_bounds__(256)
void proj_kernel(const float* __restrict__ x, const unsigned short* __restrict__ WT,
                 unsigned short* __restrict__ Qb, unsigned short* __restrict__ Kb,
                 unsigned short* __restrict__ Vb) {
    const int w = threadIdx.x >> 6;
    const int l = threadIdx.x & 63;
    const int ln = l & 15;
    const int lg = l >> 4;
    const int m0 = blockIdx.x * 64 + w * 16;

    f32x4 acc[3][4];
#pragma unroll
    for (int a = 0; a < 3; ++a)
#pragma unroll
        for (int f = 0; f < 4; ++f)
            acc[a][f] = (f32x4){0.f, 0.f, 0.f, 0.f};

    const float* xrow = x + (size_t)(m0 + ln) * C_;

#pragma unroll
    for (int kk = 0; kk < 8; ++kk) {
        const int kb = kk * 32 + lg * 8;
        float4 xa = *(const float4*)(xrow + kb);
        float4 xb = *(const float4*)(xrow + kb + 4);
        bf16x8 a = cvt8(xa, xb);
#pragma unroll
        for (int ws_ = 0; ws_ < 3; ++ws_) {
#pragma unroll
            for (int f = 0; f < 4; ++f) {
                const bf16x8 bfr = *(const bf16x8*)(WT + (size_t)ws_ * HS_ * C_
                                                    + (size_t)(16 * f + ln) * C_ + kb);
                acc[ws_][f] = __builtin_amdgcn_mfma_f32_16x16x32_bf16(a, bfr, acc[ws_][f], 0, 0, 0);
            }
        }
    }

    unsigned short* dsts[3] = {Qb, Kb, Vb};
#pragma unroll
    for (int ws_ = 0; ws_ < 3; ++ws_) {
#pragma unroll
        for (int f = 0; f < 4; ++f) {
#pragma unroll
            for (int r = 0; r < 4; ++r) {
                int row = m0 + lg * 4 + r;
                dsts[ws_][(size_t)row * HS_ + 16 * f + ln] = f2bf(acc[ws_][f][r]);
            }
        }
    }
}

// ---- Kernel 2: flash-style causal attention ----
__global__ __launch_bounds__(256)
void attn_kernel(const unsigned short* __restrict__ Qb, const unsigned short* __restrict__ Kb,
                 const unsigned short* __restrict__ Vb, float* __restrict__ out) {
    __shared__ unsigned short P_lds[4][16][40];   // per-wave 16x32 P tile, padded rows

    const int w = threadIdx.x >> 6;
    const int l = threadIdx.x & 63;
    const int ln = l & 15;
    const int lg = l >> 4;
    const int b = blockIdx.x >> 2;
    const int qt = blockIdx.x & 3;
    const int q0 = qt * 64;
    const int r0 = q0 + w * 16;
    const size_t base = (size_t)b * T_ * HS_;
    const float scale = 0.0625f;   // C^-0.5 = 1/16

    // Q fragments (A operand), rows r0..r0+15, K halves
    bf16x8 qa[2];
#pragma unroll
    for (int kk = 0; kk < 2; ++kk)
        qa[kk] = *(const bf16x8*)(Qb + base + (size_t)(r0 + ln) * HS_ + kk * 32 + lg * 8);

    float m[4], lsum[4];
    f32x4 o[4];
#pragma unroll
    for (int r = 0; r < 4; ++r) { m[r] = -INFINITY; lsum[r] = 0.f; }
#pragma unroll
    for (int f = 0; f < 4; ++f) o[f] = (f32x4){0.f, 0.f, 0.f, 0.f};

    const int nkt = qt * 2 + 2;
    for (int kt = 0; kt < nkt; ++kt) {
        const int n0 = kt * 32;

        // S = Q K^T  (two 16-col halves)
        f32x4 s[2];
#pragma unroll
        for (int h = 0; h < 2; ++h) {
            bf16x8 kb0 = *(const bf16x8*)(Kb + base + (size_t)(n0 + 16 * h + ln) * HS_ + lg * 8);
            bf16x8 kb1 = *(const bf16x8*)(Kb + base + (size_t)(n0 + 16 * h + ln) * HS_ + 32 + lg * 8);
            f32x4 z = (f32x4){0.f, 0.f, 0.f, 0.f};
            z = __builtin_amdgcn_mfma_f32_16x16x32_bf16(qa[0], kb0, z, 0, 0, 0);
            s[h] = __builtin_amdgcn_mfma_f32_16x16x32_bf16(qa[1], kb1, z, 0, 0, 0);
        }

        // scale + causal mask
        float sm[2][4];
#pragma unroll
        for (int r = 0; r < 4; ++r) {
            const int qrow = r0 + lg * 4 + r;
#pragma unroll
            for (int h = 0; h < 2; ++h) {
                float v = s[h][r] * scale;
                sm[h][r] = (qrow >= n0 + 16 * h + ln) ? v : -INFINITY;
            }
        }

        // online softmax: row reductions across the 16-lane col group
        float fac[4], p[2][4];
#pragma unroll
        for (int r = 0; r < 4; ++r) {
            float tmax = fmaxf(sm[0][r], sm[1][r]);
#pragma unroll
            for (int mask = 1; mask < 16; mask <<= 1)
                tmax = fmaxf(tmax, __shfl_xor(tmax, mask, 64));
            float mn = fmaxf(m[r], tmax);
            fac[r] = __expf(m[r] - mn);        // m[r]=-inf,mn finite -> 0
            p[0][r] = __expf(sm[0][r] - mn);
            p[1][r] = __expf(sm[1][r] - mn);
            float rs = p[0][r] + p[1][r];
#pragma unroll
            for (int mask = 1; mask < 16; mask <<= 1)
                rs += __shfl_xor(rs, mask, 64);
            lsum[r] = lsum[r] * fac[r] + rs;
            m[r] = mn;
        }
#pragma unroll
        for (int f = 0; f < 4; ++f)
#pragma unroll
            for (int r = 0; r < 4; ++r)
                o[f][r] *= fac[r];

        // P -> LDS (bf16), re-fragment as PV A operand
#pragma unroll
        for (int h = 0; h < 2; ++h)
#pragma unroll
            for (int r = 0; r < 4; ++r)
                P_lds[w][lg * 4 + r][16 * h + ln] = f2bf(p[h][r]);

        bf16x8 pa = *(const bf16x8*)(&P_lds[w][ln][lg * 8]);

        // PV: V B-fragments (strided scalar loads, L1-resident tile)
#pragma unroll
        for (int f = 0; f < 4; ++f) {
            bf16x8 vb;
#pragma unroll
            for (int j = 0; j < 8; ++j)
                vb[j] = (short)Vb[base + (size_t)(n0 + lg * 8 + j) * HS_ + 16 * f + ln];
            o[f] = __builtin_amdgcn_mfma_f32_16x16x32_bf16(pa, vb, o[f], 0, 0, 0);
        }
    }

    // epilogue: normalize and store fp32
#pragma unroll
    for (int f = 0; f < 4; ++f)
#pragma unroll
        for (int r = 0; r < 4; ++r) {
            int trow = r0 + lg * 4 + r;
            out[base + (size_t)trow * HS_ + 16 * f + ln] = o[f][r] / lsum[r];
        }
}

extern "C" void kernel_launch(void* const* d_in, const int* in_sizes, int n_in,
                              void* d_out, int out_size, void* d_ws, size_t ws_size,
                              hipStream_t stream) {
    const float* x  = (const float*)d_in[0];
    const float* Wq = (const float*)d_in[1];
    const float* Wk = (const float*)d_in[2];
    const float* Wv = (const float*)d_in[3];
    float* out = (float*)d_out;

    unsigned short* WT = (unsigned short*)d_ws;                 // 3*64*256
    unsigned short* Qb = WT + 3 * HS_ * C_;                     // B*T*64
    unsigned short* Kb = Qb + (size_t)B_ * T_ * HS_;
    unsigned short* Vb = Kb + (size_t)B_ * T_ * HS_;

    wt_kernel<<<(3 * HS_ * C_ + 255) / 256, 256, 0, stream>>>(Wq, Wk, Wv, WT);
    proj_kernel<<<(B_ * T_) / 64, 256, 0, stream>>>(x, WT, Qb, Kb, Vb);
    attn_kernel<<<B_ * 4, 256, 0, stream>>>(Qb, Kb, Vb, out);
}

// Round 2
// 135.943 us; speedup vs baseline: 1.2371x; 1.2371x over previous
//
#include <hip/hip_runtime.h>
#include <hip/hip_bf16.h>
#include <cstdint>
#include <cmath>

#define B_ 512
#define T_ 256
#define C_ 256
#define HS_ 64

typedef short bf16x8 __attribute__((ext_vector_type(8)));
typedef float f32x4 __attribute__((ext_vector_type(4)));

static __device__ __forceinline__ unsigned short f2bf(float f) {
    union { float f; unsigned int u; } v; v.f = f;
    unsigned int r = v.u + 0x7fffu + ((v.u >> 16) & 1u);
    return (unsigned short)(r >> 16);
}

// ---- Kernel 0: W transpose + bf16 convert: WT[w][n][k] = W_w[k][n] ----
__global__ void wt_kernel(const float* __restrict__ Wq, const float* __restrict__ Wk,
                          const float* __restrict__ Wv, unsigned short* __restrict__ WT) {
    int idx = blockIdx.x * 256 + threadIdx.x;
    if (idx >= 3 * HS_ * C_) return;
    int w = idx / (HS_ * C_);
    int rem = idx - w * (HS_ * C_);
    int n = rem / C_;
    int k = rem - n * C_;
    const float* W = (w == 0) ? Wq : ((w == 1) ? Wk : Wv);
    WT[idx] = f2bf(W[k * HS_ + n]);
}

// ---- Kernel 1: projection GEMM, LDS-staged. Q/K/V bf16 [B*T][64] ----
// Block: 256 threads (4 waves), 128 rows. Wave: 32 rows x 64 cols x 3 mats.
__global__ __launch_bounds__(256)
void proj_kernel(const float* __restrict__ x, const unsigned short* __restrict__ WT,
                 unsigned short* __restrict__ Qb, unsigned short* __restrict__ Kb,
                 unsigned short* __restrict__ Vb) {
    __shared__ unsigned short xt[128 * 256];   // 64 KB, XOR-swizzled per row
    const int tid = threadIdx.x;
    const int w = tid >> 6;
    const int l = tid & 63;
    const int ln = l & 15;
    const int lg = l >> 4;
    const int m0 = blockIdx.x * 128;

    // ---- stage x -> LDS (bf16), coalesced float4 reads ----
    // each pass: 4 rows; 64 lanes cover one full row (64 x float4 = 256 floats)
#pragma unroll
    for (int p = 0; p < 32; ++p) {
        const int row = p * 4 + (tid >> 6);
        const int c4 = (tid & 63) * 4;                       // float col
        float4 v = *(const float4*)(x + (size_t)(m0 + row) * C_ + c4);
        ushort4 hh;
        hh.x = f2bf(v.x); hh.y = f2bf(v.y); hh.z = f2bf(v.z); hh.w = f2bf(v.w);
        char* dst = (char*)xt + row * 512 + ((c4 * 2) ^ ((row & 7) << 4));
        *(ushort4*)dst = hh;
    }
    __syncthreads();

    f32x4 acc[2][3][4];
#pragma unroll
    for (int t = 0; t < 2; ++t)
#pragma unroll
        for (int a = 0; a < 3; ++a)
#pragma unroll
            for (int f = 0; f < 4; ++f)
                acc[t][a][f] = (f32x4){0.f, 0.f, 0.f, 0.f};

    // ---- main loop over K in 2 halves of 128 ----
#pragma unroll
    for (int h = 0; h < 2; ++h) {
        // A-side (x rows) fragments from LDS: rows w*32 + t*16 + ln, k-chunks
        bf16x8 afr[2][4];
#pragma unroll
        for (int t = 0; t < 2; ++t)
#pragma unroll
            for (int kk = 0; kk < 4; ++kk) {
                const int row = w * 32 + t * 16 + ln;
                const int off = (((h * 4 + kk) * 64 + lg * 16) ^ ((row & 7) << 4));
                afr[t][kk] = *(const bf16x8*)((const char*)xt + row * 512 + off);
            }
#pragma unroll
        for (int ws_ = 0; ws_ < 3; ++ws_) {
#pragma unroll
            for (int f = 0; f < 4; ++f) {
                const unsigned short* wrow = WT + (size_t)ws_ * HS_ * C_
                                             + (size_t)(16 * f + ln) * C_ + h * 128 + lg * 8;
                bf16x8 bfr[4];
#pragma unroll
                for (int kk = 0; kk < 4; ++kk)
                    bfr[kk] = *(const bf16x8*)(wrow + kk * 32);
#pragma unroll
                for (int t = 0; t < 2; ++t)
#pragma unroll
                    for (int kk = 0; kk < 4; ++kk)
                        acc[t][ws_][f] = __builtin_amdgcn_mfma_f32_16x16x32_bf16(
                            bfr[kk], afr[t][kk], acc[t][ws_][f], 0, 0, 0);
            }
        }
    }

    // ---- store: lane holds out[row=ln][cols f*16+lg*4 .. +3] -> ushort4 ----
    unsigned short* dsts[3] = {Qb, Kb, Vb};
#pragma unroll
    for (int t = 0; t < 2; ++t)
#pragma unroll
        for (int ws_ = 0; ws_ < 3; ++ws_)
#pragma unroll
            for (int f = 0; f < 4; ++f) {
                const int row = m0 + w * 32 + t * 16 + ln;
                ushort4 o;
                o.x = f2bf(acc[t][ws_][f][0]);
                o.y = f2bf(acc[t][ws_][f][1]);
                o.z = f2bf(acc[t][ws_][f][2]);
                o.w = f2bf(acc[t][ws_][f][3]);
                *(ushort4*)(dsts[ws_] + (size_t)row * HS_ + f * 16 + lg * 4) = o;
            }
}

// ---- Kernel 2: flash-style causal attention (unchanged from round 1) ----
__global__ __launch_bounds__(256)
void attn_kernel(const unsigned short* __restrict__ Qb, const unsigned short* __restrict__ Kb,
                 const unsigned short* __restrict__ Vb, float* __restrict__ out) {
    __shared__ unsigned short P_lds[4][16][40];

    const int w = threadIdx.x >> 6;
    const int l = threadIdx.x & 63;
    const int ln = l & 15;
    const int lg = l >> 4;
    const int b = blockIdx.x >> 2;
    const int qt = blockIdx.x & 3;
    const int q0 = qt * 64;
    const int r0 = q0 + w * 16;
    const size_t base = (size_t)b * T_ * HS_;
    const float scale = 0.0625f;

    bf16x8 qa[2];
#pragma unroll
    for (int kk = 0; kk < 2; ++kk)
        qa[kk] = *(const bf16x8*)(Qb + base + (size_t)(r0 + ln) * HS_ + kk * 32 + lg * 8);

    float m[4], lsum[4];
    f32x4 o[4];
#pragma unroll
    for (int r = 0; r < 4; ++r) { m[r] = -INFINITY; lsum[r] = 0.f; }
#pragma unroll
    for (int f = 0; f < 4; ++f) o[f] = (f32x4){0.f, 0.f, 0.f, 0.f};

    const int nkt = qt * 2 + 2;
    for (int kt = 0; kt < nkt; ++kt) {
        const int n0 = kt * 32;

        f32x4 s[2];
#pragma unroll
        for (int h = 0; h < 2; ++h) {
            bf16x8 kb0 = *(const bf16x8*)(Kb + base + (size_t)(n0 + 16 * h + ln) * HS_ + lg * 8);
            bf16x8 kb1 = *(const bf16x8*)(Kb + base + (size_t)(n0 + 16 * h + ln) * HS_ + 32 + lg * 8);
            f32x4 z = (f32x4){0.f, 0.f, 0.f, 0.f};
            z = __builtin_amdgcn_mfma_f32_16x16x32_bf16(qa[0], kb0, z, 0, 0, 0);
            s[h] = __builtin_amdgcn_mfma_f32_16x16x32_bf16(qa[1], kb1, z, 0, 0, 0);
        }

        float sm[2][4];
#pragma unroll
        for (int r = 0; r < 4; ++r) {
            const int qrow = r0 + lg * 4 + r;
#pragma unroll
            for (int h = 0; h < 2; ++h) {
                float v = s[h][r] * scale;
                sm[h][r] = (qrow >= n0 + 16 * h + ln) ? v : -INFINITY;
            }
        }

        float fac[4], p[2][4];
#pragma unroll
        for (int r = 0; r < 4; ++r) {
            float tmax = fmaxf(sm[0][r], sm[1][r]);
#pragma unroll
            for (int mask = 1; mask < 16; mask <<= 1)
                tmax = fmaxf(tmax, __shfl_xor(tmax, mask, 64));
            float mn = fmaxf(m[r], tmax);
            fac[r] = __expf(m[r] - mn);
            p[0][r] = __expf(sm[0][r] - mn);
            p[1][r] = __expf(sm[1][r] - mn);
            float rs = p[0][r] + p[1][r];
#pragma unroll
            for (int mask = 1; mask < 16; mask <<= 1)
                rs += __shfl_xor(rs, mask, 64);
            lsum[r] = lsum[r] * fac[r] + rs;
            m[r] = mn;
        }
#pragma unroll
        for (int f = 0; f < 4; ++f)
#pragma unroll
            for (int r = 0; r < 4; ++r)
                o[f][r] *= fac[r];

#pragma unroll
        for (int h = 0; h < 2; ++h)
#pragma unroll
            for (int r = 0; r < 4; ++r)
                P_lds[w][lg * 4 + r][16 * h + ln] = f2bf(p[h][r]);

        bf16x8 pa = *(const bf16x8*)(&P_lds[w][ln][lg * 8]);

#pragma unroll
        for (int f = 0; f < 4; ++f) {
            bf16x8 vb;
#pragma unroll
            for (int j = 0; j < 8; ++j)
                vb[j] = (short)Vb[base + (size_t)(n0 + lg * 8 + j) * HS_ + 16 * f + ln];
            o[f] = __builtin_amdgcn_mfma_f32_16x16x32_bf16(pa, vb, o[f], 0, 0, 0);
        }
    }

#pragma unroll
    for (int f = 0; f < 4; ++f)
#pragma unroll
        for (int r = 0; r < 4; ++r) {
            int trow = r0 + lg * 4 + r;
            out[base + (size_t)trow * HS_ + 16 * f + ln] = o[f][r] / lsum[r];
        }
}

extern "C" void kernel_launch(void* const* d_in, const int* in_sizes, int n_in,
                              void* d_out, int out_size, void* d_ws, size_t ws_size,
                              hipStream_t stream) {
    const float* x  = (const float*)d_in[0];
    const float* Wq = (const float*)d_in[1];
    const float* Wk = (const float*)d_in[2];
    const float* Wv = (const float*)d_in[3];
    float* out = (float*)d_out;

    unsigned short* WT = (unsigned short*)d_ws;                 // 3*64*256
    unsigned short* Qb = WT + 3 * HS_ * C_;                     // B*T*64
    unsigned short* Kb = Qb + (size_t)B_ * T_ * HS_;
    unsigned short* Vb = Kb + (size_t)B_ * T_ * HS_;

    wt_kernel<<<(3 * HS_ * C_ + 255) / 256, 256, 0, stream>>>(Wq, Wk, Wv, WT);
    proj_kernel<<<(B_ * T_) / 128, 256, 0, stream>>>(x, WT, Qb, Kb, Vb);
    attn_kernel<<<B_ * 4, 256, 0, stream>>>(Qb, Kb, Vb, out);
}